// Round 18
// baseline (146.643 us; speedup 1.0000x reference)
//
#include <hip/hip_runtime.h>

#define NN 100000
#define NE 1600000
// IN_CH = HID = 64, OUT_CH = 16

// ---- bucketed CSR build geometry ----
#define BSHIFT 9
#define BWIDTH 512
#define NBUCK 196
#define SLOTS 12288
#define CHUNK 4096                               // edges per B1 block
#define B1_BLOCKS ((NE + CHUNK - 1) / CHUNK)     // 391
#define GEMM_BLOCKS ((NN + 63) / 64)             // 1563
#define AGG_CAP 1024                             // 8-node agg2 blocks
#define FUSE_CAP 2048                            // 64-node fused blocks

typedef float    v2f __attribute__((ext_vector_type(2)));
typedef unsigned v2u __attribute__((ext_vector_type(2)));
typedef short    bf16x8 __attribute__((ext_vector_type(8)));
typedef float    f32x4  __attribute__((ext_vector_type(4)));

// ---- bf16 helpers (RNE pack, exact unpack) ----
__device__ __forceinline__ float u2f(unsigned u) {
    union { unsigned u; float f; } v; v.u = u; return v.f;
}
__device__ __forceinline__ unsigned f2u(float f) {
    union { float f; unsigned u; } v; v.f = f; return v.u;
}
__device__ __forceinline__ unsigned f2bf(float f) {   // bf16 in low 16, RNE
    unsigned u = f2u(f);
    return (u + 0x7FFFu + ((u >> 16) & 1u)) >> 16;
}
__device__ __forceinline__ v2f unpk(unsigned x) {
    v2u w; w[0] = x << 16; w[1] = x & 0xFFFF0000u;
    union { v2u u; v2f f; } c; c.u = w; return c.f;
}
// wave-level inclusive scan (64 lanes)
__device__ __forceinline__ int wave_incl_scan(int v, int lane) {
    #pragma unroll
    for (int off = 1; off < 64; off <<= 1) {
        int u = __shfl_up(v, off);
        if (lane >= off) v += u;
    }
    return v;
}

// ---------------------------------------------------------------------------
// Detect int64 vs int32 edge_index; also zeroes bcnt.
__global__ void detect_mode_kernel(const int* ei32, int* flag, int* bcnt) {
    __shared__ int any_nonzero;
    if (threadIdx.x == 0) any_nonzero = 0;
    if (threadIdx.x < NBUCK) bcnt[threadIdx.x] = 0;
    __syncthreads();
    int idx = 1 + 2 * threadIdx.x;
    if (ei32[idx] != 0) atomicOr(&any_nonzero, 1);
    __syncthreads();
    if (threadIdx.x == 0) flag[0] = (any_nonzero == 0) ? 1 : 0;  // 1 => int64
}

__device__ __forceinline__ void load_edge(const void* ei, int is64, int e,
                                          int& s, int& d) {
    if (is64) {
        const long long* p = (const long long*)ei;
        s = (int)p[e];
        d = (int)p[NE + e];
    } else {
        const int* p = (const int*)ei;
        s = p[e];
        d = p[NE + e];
    }
}

// ---------------------------------------------------------------------------
// MFMA GEMM body (layer 1, f32 input): t(bf16) = feat @ Wl.T ;
// r(bf16, +bias) = feat @ Wr.T. 4 waves, tile 64n x 128c.
__device__ __forceinline__ void gemm_mfma_body_f32(
    char* smem, const float* __restrict__ featf,
    const float* __restrict__ Wl, const float* __restrict__ Wr,
    const float* __restrict__ bias,
    unsigned* __restrict__ outt, unsigned* __restrict__ outr,
    int tile, int t)
{
    unsigned short* Als = (unsigned short*)smem;            // [64][72] bf16
    unsigned short* Bls = (unsigned short*)(smem + 9216);   // [128][72] bf16
    const int lane = t & 63, w = t >> 6;
    const int m0 = tile * 64;

    #pragma unroll
    for (int rep = 0; rep < 2; ++rep) {
        int task = t + 256 * rep;
        int row = task >> 3, s = task & 7;
        int gn = m0 + row;
        uint4 u;
        if (gn < NN) {
            float4 v0 = *(const float4*)(featf + (size_t)gn * 64 + 8 * s);
            float4 v1 = *(const float4*)(featf + (size_t)gn * 64 + 8 * s + 4);
            u.x = f2bf(v0.x) | (f2bf(v0.y) << 16);
            u.y = f2bf(v0.z) | (f2bf(v0.w) << 16);
            u.z = f2bf(v1.x) | (f2bf(v1.y) << 16);
            u.w = f2bf(v1.z) | (f2bf(v1.w) << 16);
        } else u = make_uint4(0u, 0u, 0u, 0u);
        *(uint4*)(Als + row * 72 + 8 * s) = u;
    }
    #pragma unroll
    for (int rep = 0; rep < 4; ++rep) {
        int task = t + 256 * rep;
        int c = task >> 3, s = task & 7;
        const float* Wsrc = (c < 64) ? (Wl + (size_t)c * 64)
                                     : (Wr + (size_t)(c - 64) * 64);
        float4 v0 = *(const float4*)(Wsrc + 8 * s);
        float4 v1 = *(const float4*)(Wsrc + 8 * s + 4);
        uint4 u;
        u.x = f2bf(v0.x) | (f2bf(v0.y) << 16);
        u.y = f2bf(v0.z) | (f2bf(v0.w) << 16);
        u.z = f2bf(v1.x) | (f2bf(v1.y) << 16);
        u.w = f2bf(v1.z) | (f2bf(v1.w) << 16);
        *(uint4*)(Bls + c * 72 + 8 * s) = u;
    }
    __syncthreads();

    const int r = lane & 15, g = lane >> 4;
    const int cw0 = 32 * w;

    bf16x8 bf[2][2];
    #pragma unroll
    for (int ct = 0; ct < 2; ++ct)
        #pragma unroll
        for (int ks = 0; ks < 2; ++ks) {
            int c = cw0 + 16 * ct + r;
            bf[ct][ks] = *(const bf16x8*)(Bls + c * 72 + (ks * 4 + g) * 8);
        }

    f32x4 acc[4][2];
    #pragma unroll
    for (int nt = 0; nt < 4; ++nt)
        #pragma unroll
        for (int ct = 0; ct < 2; ++ct)
            acc[nt][ct] = (f32x4){0.f, 0.f, 0.f, 0.f};

    #pragma unroll
    for (int nt = 0; nt < 4; ++nt) {
        bf16x8 af[2];
        #pragma unroll
        for (int ks = 0; ks < 2; ++ks)
            af[ks] = *(const bf16x8*)(Als + (nt * 16 + r) * 72 + (ks * 4 + g) * 8);
        #pragma unroll
        for (int ct = 0; ct < 2; ++ct)
            #pragma unroll
            for (int ks = 0; ks < 2; ++ks)
                acc[nt][ct] = __builtin_amdgcn_mfma_f32_16x16x32_bf16(
                    af[ks], bf[ct][ks], acc[nt][ct], 0, 0, 0);
    }

    unsigned short* Tb = (unsigned short*)outt;
    unsigned short* Rb = (unsigned short*)outr;
    #pragma unroll
    for (int ct = 0; ct < 2; ++ct) {
        int c = cw0 + 16 * ct + r;
        float badd = (c >= 64) ? bias[c - 64] : 0.f;
        unsigned short* dst = (c < 64) ? (Tb + c) : (Rb + (c - 64));
        #pragma unroll
        for (int nt = 0; nt < 4; ++nt)
            #pragma unroll
            for (int i = 0; i < 4; ++i) {
                int row = m0 + nt * 16 + g * 4 + i;
                if (row < NN)
                    dst[(size_t)row * 64] = (unsigned short)f2bf(acc[nt][ct][i] + badd);
            }
    }
}

// ---------------------------------------------------------------------------
// FUSED: blocks [0, B1_BLOCKS) bucket edges; blocks [B1_BLOCKS, ..) layer-1 GEMM.
__global__ __launch_bounds__(256) void b1_gemm1_kernel(
    const void* ei, const int* flag,
    int* __restrict__ bcnt, int* __restrict__ bpk,
    const float* __restrict__ x,
    const float* __restrict__ W1l, const float* __restrict__ W1r,
    const float* __restrict__ b1,
    unsigned* __restrict__ T, unsigned* __restrict__ R)
{
    __shared__ __align__(16) char smem[27648];
    const int t = threadIdx.x;

    if (blockIdx.x >= B1_BLOCKS) {
        if (blockIdx.x == B1_BLOCKS && t < 32) T[(size_t)NN * 32 + t] = 0u; // zero row
        gemm_mfma_body_f32(smem, x, W1l, W1r, b1, T, R, blockIdx.x - B1_BLOCKS, t);
        return;
    }

    // ---------------- B1 part ----------------
    int* stage = (int*)smem;                                     // 16384
    unsigned char* sbuck = (unsigned char*)(smem + 16384);       // 4096
    int* hist  = (int*)(smem + 20480);                           // 784
    int* scanb = (int*)(smem + 21264);
    int* gbase = (int*)(smem + 22048);
    int* lofs  = (int*)(smem + 22832);
    int* wsum  = (int*)(smem + 23616);                           // 16

    const int is64 = *flag;
    const int e0 = blockIdx.x * CHUNK;
    const int nE = min(CHUNK, NE - e0);
    const int lane = t & 63, wvi = t >> 6;

    for (int i = t; i < NBUCK; i += 256) { hist[i] = 0; lofs[i] = 0; }
    __syncthreads();

    int sr[16], dr[16];
    #pragma unroll
    for (int rr = 0; rr < 16; ++rr) {
        int e = e0 + t + 256 * rr;
        if (e < NE) load_edge(ei, is64, e, sr[rr], dr[rr]);
        else dr[rr] = -1;
    }
    #pragma unroll
    for (int rr = 0; rr < 16; ++rr)
        if (dr[rr] >= 0) atomicAdd(&hist[dr[rr] >> BSHIFT], 1);
    __syncthreads();

    int v = (t < NBUCK) ? hist[t] : 0;
    int s = wave_incl_scan(v, lane);
    if (lane == 63) wsum[wvi] = s;
    __syncthreads();
    int add = 0;
    #pragma unroll
    for (int k = 0; k < 3; ++k) if (wvi > k) add += wsum[k];
    s += add;
    if (t < NBUCK) {
        scanb[t] = s - v;
        gbase[t] = atomicAdd(&bcnt[t], v);
    }
    __syncthreads();

    #pragma unroll
    for (int rr = 0; rr < 16; ++rr) {
        if (dr[rr] >= 0) {
            int b = dr[rr] >> BSHIFT;
            int p = scanb[b] + atomicAdd(&lofs[b], 1);
            stage[p] = (sr[rr] << BSHIFT) | (dr[rr] & (BWIDTH - 1));
            sbuck[p] = (unsigned char)b;
        }
    }
    __syncthreads();

    for (int i = t; i < nE; i += 256) {
        int b = sbuck[i];
        int off = gbase[b] + (i - scanb[b]);
        if (off < SLOTS) bpk[(size_t)b * SLOTS + off] = stage[i];
    }
}

// ---------------------------------------------------------------------------
// B3 (512 threads): packed bucket -> rowptr + colb (byte offsets), with
// in-block bucket prefix; all scans via wave shfl.
__global__ __launch_bounds__(512) void bucket_to_csr_kernel(
    const int* __restrict__ bcnt, const int* __restrict__ bpk,
    int* __restrict__ rowptr, int* __restrict__ colb)
{
    __shared__ int ldeg[512], lptr[512], lcnt[512], sc[512], wsum[8];
    const int t = threadIdx.x, b = blockIdx.x;
    const int lane = t & 63, wvi = t >> 6;

    int v = (t < NBUCK) ? bcnt[t] : 0;
    int s = wave_incl_scan(v, lane);
    if (lane == 63) wsum[wvi] = s;
    __syncthreads();
    int add = 0;
    #pragma unroll
    for (int k = 0; k < 7; ++k) if (wvi > k) add += wsum[k];
    s += add;
    sc[t] = s;
    __syncthreads();
    const int base = (b == 0) ? 0 : sc[b - 1];
    if (b == 0 && t == 0) rowptr[NN] = NE;
    __syncthreads();

    ldeg[t] = 0; lcnt[t] = 0;
    __syncthreads();

    const int n0 = b << BSHIFT;
    const int cnt = min(bcnt[b], SLOTS);
    const int* src = bpk + (size_t)b * SLOTS;
    for (int i = t; i < cnt; i += 512)
        atomicAdd(&ldeg[src[i] & (BWIDTH - 1)], 1);
    __syncthreads();

    int a = ldeg[t];
    int s2 = wave_incl_scan(a, lane);
    if (lane == 63) wsum[wvi] = s2;
    __syncthreads();
    int add2 = 0;
    #pragma unroll
    for (int k = 0; k < 7; ++k) if (wvi > k) add2 += wsum[k];
    s2 += add2;
    lptr[t] = s2 - a;
    __syncthreads();

    int gn = n0 + t;
    if (gn < NN) rowptr[gn] = base + lptr[t];

    for (int i = t; i < cnt; i += 512) {
        int p = src[i];
        int li = p & (BWIDTH - 1);
        int pos = lptr[li] + atomicAdd(&lcnt[li], 1);
        colb[base + pos] = (p >> BSHIFT) << 7;   // src byte offset into table
    }
}

// ---------------------------------------------------------------------------
#define AGG_STEP(O0, O1, O2, O3)                                              \
    {                                                                         \
        int o0 = O0, o1 = O1, o2 = O2, o3 = O3;                               \
        o0 = (jj      < end) ? o0 : zoff;                                     \
        o1 = (jj + 4  < end) ? o1 : zoff;                                     \
        o2 = (jj + 8  < end) ? o2 : zoff;                                     \
        o3 = (jj + 12 < end) ? o3 : zoff;                                     \
        uint4 u0 = *(const uint4*)(tb + (size_t)(unsigned)o0 + 16 * c8);      \
        uint4 u1 = *(const uint4*)(tb + (size_t)(unsigned)o1 + 16 * c8);      \
        uint4 u2 = *(const uint4*)(tb + (size_t)(unsigned)o2 + 16 * c8);      \
        uint4 u3 = *(const uint4*)(tb + (size_t)(unsigned)o3 + 16 * c8);      \
        a0 += unpk(u0.x); a1 += unpk(u0.y); a2 += unpk(u0.z); a3 += unpk(u0.w);\
        b0 += unpk(u1.x); b1 += unpk(u1.y); b2 += unpk(u1.z); b3 += unpk(u1.w);\
        a0 += unpk(u2.x); a1 += unpk(u2.y); a2 += unpk(u2.z); a3 += unpk(u2.w);\
        b0 += unpk(u3.x); b1 += unpk(u3.y); b2 += unpk(u3.z); b3 += unpk(u3.w);\
    }

// ---------------------------------------------------------------------------
// FUSED agg1 + gemm2. Block = one 64-node tile (matches gemm tile).
// Phase A: stage W2 into Bls; stage the tile's contiguous col range; then
// 8 rounds x (4 waves x 2 nodes) of gather-mean; h1 = relu(mean + r1) packed
// bf16 DIRECTLY into the MFMA A-tile (Als). Same rounding as the unfused
// path -> identical numerics. Phase B: MFMA -> t2 (to T2, NOT T: other
// blocks still gather from t1) and r2 (to R; tile-local, read-before-write).
__global__ __launch_bounds__(256) void agg1_gemm2_kernel(
    const int* __restrict__ rowptr, const int* __restrict__ colb,
    const unsigned* __restrict__ tt,   // t1 table (NN+1) x 32
    unsigned* __restrict__ rh,         // r1 in / r2 out, NN x 32
    const float* __restrict__ W2l, const float* __restrict__ W2r,
    const float* __restrict__ b2,
    unsigned* __restrict__ outt2)      // t2 table (NN+1) x 32
{
    __shared__ __align__(16) char smem[36864];
    unsigned short* Als = (unsigned short*)smem;             // [64][72] bf16
    unsigned short* Bls = (unsigned short*)(smem + 9216);    // [128][72] bf16
    int* lcol = (int*)(smem + 9216 + 18432);                 // FUSE_CAP ints

    const int t = threadIdx.x;
    const int lane = t & 63, w = t >> 6;
    const int m0 = blockIdx.x * 64;

    if (blockIdx.x == 0 && t < 32) outt2[(size_t)NN * 32 + t] = 0u;  // zero row

    // ---- stage B (W2l|W2r) ----
    #pragma unroll
    for (int rep = 0; rep < 4; ++rep) {
        int task = t + 256 * rep;
        int c = task >> 3, s = task & 7;
        const float* Wsrc = (c < 64) ? (W2l + (size_t)c * 64)
                                     : (W2r + (size_t)(c - 64) * 64);
        float4 v0 = *(const float4*)(Wsrc + 8 * s);
        float4 v1 = *(const float4*)(Wsrc + 8 * s + 4);
        uint4 u;
        u.x = f2bf(v0.x) | (f2bf(v0.y) << 16);
        u.y = f2bf(v0.z) | (f2bf(v0.w) << 16);
        u.z = f2bf(v1.x) | (f2bf(v1.y) << 16);
        u.w = f2bf(v1.z) | (f2bf(v1.w) << 16);
        *(uint4*)(Bls + c * 72 + 8 * s) = u;
    }

    // ---- stage the tile's col range ----
    const int nend = min(m0 + 64, NN);
    const int cbeg = rowptr[m0];
    const int cendB = rowptr[nend];
    const int total = cendB - cbeg;
    const bool fast = (total <= FUSE_CAP);
    if (fast) {
        for (int i = t; i < total; i += 256) lcol[i] = colb[cbeg + i];
    }
    __syncthreads();

    // ---- Phase A: aggregate 8 rounds, h1 -> Als ----
    const int half = lane >> 5;
    const int slot = (lane >> 3) & 3;
    const int c8   = lane & 7;
    const char* tb = (const char*)tt;
    const int zoff = NN * 128;

    #pragma unroll 1
    for (int rnd = 0; rnd < 8; ++rnd) {
        const int row = rnd * 8 + 2 * w + half;
        const int node = m0 + row;
        int beg = 0, end = 0;
        if (node < NN) { beg = rowptr[node]; end = rowptr[node + 1]; }
        const int deg = end - beg;
        int niter = (deg + 3) >> 2;
        niter = max(niter, __shfl_xor(niter, 32));

        v2f a0 = {0.f, 0.f}, a1 = {0.f, 0.f}, a2 = {0.f, 0.f}, a3 = {0.f, 0.f};
        v2f b0 = {0.f, 0.f}, b1 = {0.f, 0.f}, b2v = {0.f, 0.f}, b3 = {0.f, 0.f};
        // alias names for macro (uses b2 as name-free): rename b2v via macro-local
        #define b2 b2v
        int jj = beg + slot;
        int it = 0;
        if (fast) {
            for (; it + 4 <= niter; it += 4, jj += 16) {
                int jc0 = min(jj,      end - 1) - cbeg;
                int jc1 = min(jj + 4,  end - 1) - cbeg;
                int jc2 = min(jj + 8,  end - 1) - cbeg;
                int jc3 = min(jj + 12, end - 1) - cbeg;
                AGG_STEP(lcol[jc0], lcol[jc1], lcol[jc2], lcol[jc3])
            }
            for (; it < niter; ++it, jj += 4) {
                int jc0 = min(jj, end - 1) - cbeg;
                int o0 = lcol[jc0];
                o0 = (jj < end) ? o0 : zoff;
                uint4 u0 = *(const uint4*)(tb + (size_t)(unsigned)o0 + 16 * c8);
                a0 += unpk(u0.x); a1 += unpk(u0.y); a2 += unpk(u0.z); a3 += unpk(u0.w);
            }
        } else {
            for (; it + 4 <= niter; it += 4, jj += 16) {
                int jc0 = min(jj,      end - 1);
                int jc1 = min(jj + 4,  end - 1);
                int jc2 = min(jj + 8,  end - 1);
                int jc3 = min(jj + 12, end - 1);
                AGG_STEP(colb[jc0], colb[jc1], colb[jc2], colb[jc3])
            }
            for (; it < niter; ++it, jj += 4) {
                int jc0 = min(jj, end - 1);
                int o0 = colb[jc0];
                o0 = (jj < end) ? o0 : zoff;
                uint4 u0 = *(const uint4*)(tb + (size_t)(unsigned)o0 + 16 * c8);
                a0 += unpk(u0.x); a1 += unpk(u0.y); a2 += unpk(u0.z); a3 += unpk(u0.w);
            }
        }
        #undef b2
        a0 += b0; a1 += b1; a2 += b2v; a3 += b3;

        a0[0] += __shfl_xor(a0[0], 8);  a0[1] += __shfl_xor(a0[1], 8);
        a1[0] += __shfl_xor(a1[0], 8);  a1[1] += __shfl_xor(a1[1], 8);
        a2[0] += __shfl_xor(a2[0], 8);  a2[1] += __shfl_xor(a2[1], 8);
        a3[0] += __shfl_xor(a3[0], 8);  a3[1] += __shfl_xor(a3[1], 8);
        a0[0] += __shfl_xor(a0[0], 16); a0[1] += __shfl_xor(a0[1], 16);
        a1[0] += __shfl_xor(a1[0], 16); a1[1] += __shfl_xor(a1[1], 16);
        a2[0] += __shfl_xor(a2[0], 16); a2[1] += __shfl_xor(a2[1], 16);
        a3[0] += __shfl_xor(a3[0], 16); a3[1] += __shfl_xor(a3[1], 16);

        if (slot == 0 && node < NN) {
            float inv = 1.0f / fmaxf((float)deg, 1.0f);
            const unsigned* p = rh + (size_t)node * 32 + 4 * c8;   // r1 (read only)
            uint4 rr = *(const uint4*)p;
            v2f q0 = unpk(rr.x), q1 = unpk(rr.y), q2 = unpk(rr.z), q3 = unpk(rr.w);
            float h0 = fmaxf(fmaf(a0[0], inv, q0[0]), 0.0f);
            float h1 = fmaxf(fmaf(a0[1], inv, q0[1]), 0.0f);
            float h2 = fmaxf(fmaf(a1[0], inv, q1[0]), 0.0f);
            float h3 = fmaxf(fmaf(a1[1], inv, q1[1]), 0.0f);
            float h4 = fmaxf(fmaf(a2[0], inv, q2[0]), 0.0f);
            float h5 = fmaxf(fmaf(a2[1], inv, q2[1]), 0.0f);
            float h6 = fmaxf(fmaf(a3[0], inv, q3[0]), 0.0f);
            float h7 = fmaxf(fmaf(a3[1], inv, q3[1]), 0.0f);
            uint4 wv4;
            wv4.x = f2bf(h0) | (f2bf(h1) << 16);
            wv4.y = f2bf(h2) | (f2bf(h3) << 16);
            wv4.z = f2bf(h4) | (f2bf(h5) << 16);
            wv4.w = f2bf(h6) | (f2bf(h7) << 16);
            *(uint4*)(Als + row * 72 + 8 * c8) = wv4;   // h1 tile row (LDS only)
        }
    }
    __syncthreads();

    // ---- Phase B: MFMA (A = h1 tile in Als) ----
    const int r = lane & 15, g = lane >> 4;
    const int cw0 = 32 * w;

    bf16x8 bf[2][2];
    #pragma unroll
    for (int ct = 0; ct < 2; ++ct)
        #pragma unroll
        for (int ks = 0; ks < 2; ++ks) {
            int c = cw0 + 16 * ct + r;
            bf[ct][ks] = *(const bf16x8*)(Bls + c * 72 + (ks * 4 + g) * 8);
        }

    f32x4 acc[4][2];
    #pragma unroll
    for (int nt = 0; nt < 4; ++nt)
        #pragma unroll
        for (int ct = 0; ct < 2; ++ct)
            acc[nt][ct] = (f32x4){0.f, 0.f, 0.f, 0.f};

    #pragma unroll
    for (int nt = 0; nt < 4; ++nt) {
        bf16x8 af[2];
        #pragma unroll
        for (int ks = 0; ks < 2; ++ks)
            af[ks] = *(const bf16x8*)(Als + (nt * 16 + r) * 72 + (ks * 4 + g) * 8);
        #pragma unroll
        for (int ct = 0; ct < 2; ++ct)
            #pragma unroll
            for (int ks = 0; ks < 2; ++ks)
                acc[nt][ct] = __builtin_amdgcn_mfma_f32_16x16x32_bf16(
                    af[ks], bf[ct][ks], acc[nt][ct], 0, 0, 0);
    }

    unsigned short* Tb = (unsigned short*)outt2;
    unsigned short* Rb = (unsigned short*)rh;
    #pragma unroll
    for (int ct = 0; ct < 2; ++ct) {
        int c = cw0 + 16 * ct + r;
        float badd = (c >= 64) ? b2[c - 64] : 0.f;
        unsigned short* dst = (c < 64) ? (Tb + c) : (Rb + (c - 64));
        #pragma unroll
        for (int nt = 0; nt < 4; ++nt)
            #pragma unroll
            for (int i = 0; i < 4; ++i) {
                int row = m0 + nt * 16 + g * 4 + i;
                if (row < NN)
                    dst[(size_t)row * 64] = (unsigned short)f2bf(acc[nt][ct][i] + badd);
            }
    }
}

// ---------------------------------------------------------------------------
// Final aggregate + fused head: out = relu(mean(t2)+r2) @ Wlin.T + blin.
// Block = 8 nodes; wls stride 68 (bank-conflict-free, round-17 fix).
__global__ void aggregate_head_kernel(const int* __restrict__ rowptr,
                                      const int* __restrict__ colb,
                                      const unsigned* __restrict__ tt,  // t2 (NN+1) x 32
                                      const unsigned* __restrict__ rh,  // r2, NN x 32
                                      const float* __restrict__ Wlin,
                                      const float* __restrict__ blin,
                                      float* __restrict__ out) {
    __shared__ int lcol[AGG_CAP];
    __shared__ float wls[16 * 68];
    __shared__ unsigned short hbuf[8][72];
    const int t = threadIdx.x;
    const int n0 = blockIdx.x * 8;
    const int lane = t & 63;
    const int w = t >> 6;
    const int half = lane >> 5;
    const int slot = (lane >> 3) & 3;
    const int c8   = lane & 7;
    const int node = n0 + 2 * w + half;           // NN % 8 == 0 -> always < NN

    const int cbeg  = rowptr[n0];
    const int cendB = rowptr[min(n0 + 8, NN)];
    const int total = cendB - cbeg;
    const bool fast = (total <= AGG_CAP);
    if (fast) {
        for (int i = t; i < total; i += 256) lcol[i] = colb[cbeg + i];
    }
    for (int i = t; i < 1024; i += 256) {
        int cc = i >> 6, k = i & 63;
        wls[cc * 68 + k] = Wlin[i];
    }
    __syncthreads();

    const int beg = rowptr[node], end = rowptr[node + 1];
    const int deg = end - beg;
    int niter = (deg + 3) >> 2;
    niter = max(niter, __shfl_xor(niter, 32));

    const char* tb = (const char*)tt;
    const int zoff = NN * 128;
    v2f a0 = {0.f, 0.f}, a1 = {0.f, 0.f}, a2 = {0.f, 0.f}, a3 = {0.f, 0.f};
    v2f b0 = {0.f, 0.f}, b1 = {0.f, 0.f}, b2 = {0.f, 0.f}, b3 = {0.f, 0.f};

    int jj = beg + slot;
    int it = 0;
    if (fast) {
        for (; it + 4 <= niter; it += 4, jj += 16) {
            int jc0 = min(jj,      end - 1) - cbeg;
            int jc1 = min(jj + 4,  end - 1) - cbeg;
            int jc2 = min(jj + 8,  end - 1) - cbeg;
            int jc3 = min(jj + 12, end - 1) - cbeg;
            AGG_STEP(lcol[jc0], lcol[jc1], lcol[jc2], lcol[jc3])
        }
        for (; it < niter; ++it, jj += 4) {
            int jc0 = min(jj, end - 1) - cbeg;
            int o0 = lcol[jc0];
            o0 = (jj < end) ? o0 : zoff;
            uint4 u0 = *(const uint4*)(tb + (size_t)(unsigned)o0 + 16 * c8);
            a0 += unpk(u0.x); a1 += unpk(u0.y); a2 += unpk(u0.z); a3 += unpk(u0.w);
        }
    } else {
        for (; it + 4 <= niter; it += 4, jj += 16) {
            int jc0 = min(jj,      end - 1);
            int jc1 = min(jj + 4,  end - 1);
            int jc2 = min(jj + 8,  end - 1);
            int jc3 = min(jj + 12, end - 1);
            AGG_STEP(colb[jc0], colb[jc1], colb[jc2], colb[jc3])
        }
        for (; it < niter; ++it, jj += 4) {
            int jc0 = min(jj, end - 1);
            int o0 = colb[jc0];
            o0 = (jj < end) ? o0 : zoff;
            uint4 u0 = *(const uint4*)(tb + (size_t)(unsigned)o0 + 16 * c8);
            a0 += unpk(u0.x); a1 += unpk(u0.y); a2 += unpk(u0.z); a3 += unpk(u0.w);
        }
    }
    a0 += b0; a1 += b1; a2 += b2; a3 += b3;

    a0[0] += __shfl_xor(a0[0], 8);  a0[1] += __shfl_xor(a0[1], 8);
    a1[0] += __shfl_xor(a1[0], 8);  a1[1] += __shfl_xor(a1[1], 8);
    a2[0] += __shfl_xor(a2[0], 8);  a2[1] += __shfl_xor(a2[1], 8);
    a3[0] += __shfl_xor(a3[0], 8);  a3[1] += __shfl_xor(a3[1], 8);
    a0[0] += __shfl_xor(a0[0], 16); a0[1] += __shfl_xor(a0[1], 16);
    a1[0] += __shfl_xor(a1[0], 16); a1[1] += __shfl_xor(a1[1], 16);
    a2[0] += __shfl_xor(a2[0], 16); a2[1] += __shfl_xor(a2[1], 16);
    a3[0] += __shfl_xor(a3[0], 16); a3[1] += __shfl_xor(a3[1], 16);

    if (slot == 0) {
        float inv = 1.0f / fmaxf((float)deg, 1.0f);
        const unsigned* p = rh + (size_t)node * 32 + 4 * c8;
        uint4 rr = *(const uint4*)p;
        v2f q0 = unpk(rr.x), q1 = unpk(rr.y), q2 = unpk(rr.z), q3 = unpk(rr.w);
        float h0 = fmaxf(fmaf(a0[0], inv, q0[0]), 0.0f);
        float h1 = fmaxf(fmaf(a0[1], inv, q0[1]), 0.0f);
        float h2 = fmaxf(fmaf(a1[0], inv, q1[0]), 0.0f);
        float h3 = fmaxf(fmaf(a1[1], inv, q1[1]), 0.0f);
        float h4 = fmaxf(fmaf(a2[0], inv, q2[0]), 0.0f);
        float h5 = fmaxf(fmaf(a2[1], inv, q2[1]), 0.0f);
        float h6 = fmaxf(fmaf(a3[0], inv, q3[0]), 0.0f);
        float h7 = fmaxf(fmaf(a3[1], inv, q3[1]), 0.0f);
        uint4 wv4;
        wv4.x = f2bf(h0) | (f2bf(h1) << 16);
        wv4.y = f2bf(h2) | (f2bf(h3) << 16);
        wv4.z = f2bf(h4) | (f2bf(h5) << 16);
        wv4.w = f2bf(h6) | (f2bf(h7) << 16);
        *(uint4*)&hbuf[2 * w + half][8 * c8] = wv4;
    }
    __syncthreads();

    if (t < 128) {
        int i = t >> 4, cc = t & 15;
        int gnode = n0 + i;
        const unsigned* hrow = (const unsigned*)hbuf[i];
        float acc = blin[cc];
        #pragma unroll
        for (int k2 = 0; k2 < 32; ++k2) {
            v2f hv = unpk(hrow[k2]);
            acc = fmaf(hv[0], wls[cc * 68 + 2 * k2], acc);
            acc = fmaf(hv[1], wls[cc * 68 + 2 * k2 + 1], acc);
        }
        if (gnode < NN)
            out[(size_t)gnode * 16 + cc] = acc;
    }
}

// ---------------------------------------------------------------------------
extern "C" void kernel_launch(void* const* d_in, const int* in_sizes, int n_in,
                              void* d_out, int out_size, void* d_ws, size_t ws_size,
                              hipStream_t stream) {
    const float* x    = (const float*)d_in[0];
    const void*  ei   = d_in[1];
    const float* W1l  = (const float*)d_in[2];
    const float* b1   = (const float*)d_in[3];
    const float* W1r  = (const float*)d_in[4];
    const float* W2l  = (const float*)d_in[5];
    const float* b2   = (const float*)d_in[6];
    const float* W2r  = (const float*)d_in[7];
    const float* Wlin = (const float*)d_in[8];
    const float* blin = (const float*)d_in[9];
    float* out = (float*)d_out;

    char* w = (char*)d_ws;
    int*      flag   = (int*)w;                                   // @ 0
    int*      bcnt   = (int*)(w + (size_t)4 * 1024);              // @ 4K
    int*      rowptr = (int*)(w + (size_t)1024 * 1024);           // @ 1M  (400 KB+4)
    int*      colb   = (int*)(w + (size_t)2 * 1024 * 1024);       // @ 2M  (6.4 MB)
    int*      bpk    = (int*)(w + (size_t)10 * 1024 * 1024);      // @ 10M (9.6 MB, dead after B3)
    unsigned* T2     = (unsigned*)(w + (size_t)10 * 1024 * 1024); // @ 10M (12.8 MB t2, aliases bpk)
    unsigned* T      = (unsigned*)(w + (size_t)30 * 1024 * 1024); // @ 30M (12.8 MB t1 + zero row)
    unsigned* R      = (unsigned*)(w + (size_t)43 * 1024 * 1024); // @ 43M (12.8 MB bf16 r1/r2)

    detect_mode_kernel<<<1, 256, 0, stream>>>((const int*)ei, flag, bcnt);

    // ---- fused: B1 (blocks 0..390) + layer-1 MFMA GEMM (blocks 391..) ----
    b1_gemm1_kernel<<<B1_BLOCKS + GEMM_BLOCKS, 256, 0, stream>>>(
        ei, flag, bcnt, bpk, x, W1l, W1r, b1, T, R);

    bucket_to_csr_kernel<<<NBUCK, 512, 0, stream>>>(bcnt, bpk, rowptr, colb);

    // ---- fused agg1 + gemm2: h1 never hits global; t2 -> T2, r2 -> R ----
    agg1_gemm2_kernel<<<GEMM_BLOCKS, 256, 0, stream>>>(
        rowptr, colb, T, R, W2l, W2r, b2, T2);

    // ---- final aggregate + fused head ----
    const int aggBlocks = (NN + 7) / 8;        // 12500
    aggregate_head_kernel<<<aggBlocks, 256, 0, stream>>>(
        rowptr, colb, T2, R, Wlin, blin, out);
}

// Round 19
// 145.039 us; speedup vs baseline: 1.0111x; 1.0111x over previous
//
#include <hip/hip_runtime.h>

#define NN 100000
#define NE 1600000
// IN_CH = HID = 64, OUT_CH = 16

// ---- bucketed CSR build geometry ----
#define BSHIFT 9
#define BWIDTH 512
#define NBUCK 196
#define SLOTS 12288
#define CHUNK 4096                               // edges per B1 block
#define B1_BLOCKS ((NE + CHUNK - 1) / CHUNK)     // 391
#define GEMM_BLOCKS ((NN + 63) / 64)             // 1563
#define AGG_CAP 1024

typedef float    v2f __attribute__((ext_vector_type(2)));
typedef unsigned v2u __attribute__((ext_vector_type(2)));
typedef short    bf16x8 __attribute__((ext_vector_type(8)));
typedef float    f32x4  __attribute__((ext_vector_type(4)));

// ---- bf16 helpers (RNE pack, exact unpack) ----
__device__ __forceinline__ float u2f(unsigned u) {
    union { unsigned u; float f; } v; v.u = u; return v.f;
}
__device__ __forceinline__ unsigned f2u(float f) {
    union { float f; unsigned u; } v; v.f = f; return v.u;
}
__device__ __forceinline__ unsigned f2bf(float f) {   // bf16 in low 16, RNE
    unsigned u = f2u(f);
    return (u + 0x7FFFu + ((u >> 16) & 1u)) >> 16;
}
__device__ __forceinline__ v2f unpk(unsigned x) {
    v2u w; w[0] = x << 16; w[1] = x & 0xFFFF0000u;
    union { v2u u; v2f f; } c; c.u = w; return c.f;
}
// wave-level inclusive scan (64 lanes)
__device__ __forceinline__ int wave_incl_scan(int v, int lane) {
    #pragma unroll
    for (int off = 1; off < 64; off <<= 1) {
        int u = __shfl_up(v, off);
        if (lane >= off) v += u;
    }
    return v;
}

// ---------------------------------------------------------------------------
// Detect int64 vs int32 edge_index; also zeroes bcnt.
__global__ void detect_mode_kernel(const int* ei32, int* flag, int* bcnt) {
    __shared__ int any_nonzero;
    if (threadIdx.x == 0) any_nonzero = 0;
    if (threadIdx.x < NBUCK) bcnt[threadIdx.x] = 0;
    __syncthreads();
    int idx = 1 + 2 * threadIdx.x;
    if (ei32[idx] != 0) atomicOr(&any_nonzero, 1);
    __syncthreads();
    if (threadIdx.x == 0) flag[0] = (any_nonzero == 0) ? 1 : 0;  // 1 => int64
}

__device__ __forceinline__ void load_edge(const void* ei, int is64, int e,
                                          int& s, int& d) {
    if (is64) {
        const long long* p = (const long long*)ei;
        s = (int)p[e];
        d = (int)p[NE + e];
    } else {
        const int* p = (const int*)ei;
        s = p[e];
        d = p[NE + e];
    }
}

// ---------------------------------------------------------------------------
// MFMA GEMM body: t(bf16) = feat @ Wl.T ; r(bf16, +bias) = feat @ Wr.T.
// Block = 256 thr = 4 waves; tile 64 nodes x 128 ch; wave w owns 32 channels.
template<int BF16IN>
__device__ __forceinline__ void gemm_mfma_body(
    char* smem, const void* __restrict__ featv,
    const float* __restrict__ Wl, const float* __restrict__ Wr,
    const float* __restrict__ bias,
    unsigned* __restrict__ outt, unsigned* __restrict__ outr,
    int tile, int t)
{
    unsigned short* Als = (unsigned short*)smem;            // [64][72] bf16
    unsigned short* Bls = (unsigned short*)(smem + 9216);   // [128][72] bf16
    const int lane = t & 63, w = t >> 6;
    const int m0 = tile * 64;
    const float*    featf = (const float*)featv;
    const unsigned* featu = (const unsigned*)featv;

    #pragma unroll
    for (int rep = 0; rep < 2; ++rep) {
        int task = t + 256 * rep;
        int row = task >> 3, s = task & 7;
        int gn = m0 + row;
        uint4 u;
        if (BF16IN) {
            u = (gn < NN) ? *(const uint4*)(featu + (size_t)gn * 32 + 4 * s)
                          : make_uint4(0u, 0u, 0u, 0u);
        } else {
            if (gn < NN) {
                float4 v0 = *(const float4*)(featf + (size_t)gn * 64 + 8 * s);
                float4 v1 = *(const float4*)(featf + (size_t)gn * 64 + 8 * s + 4);
                u.x = f2bf(v0.x) | (f2bf(v0.y) << 16);
                u.y = f2bf(v0.z) | (f2bf(v0.w) << 16);
                u.z = f2bf(v1.x) | (f2bf(v1.y) << 16);
                u.w = f2bf(v1.z) | (f2bf(v1.w) << 16);
            } else u = make_uint4(0u, 0u, 0u, 0u);
        }
        *(uint4*)(Als + row * 72 + 8 * s) = u;
    }
    #pragma unroll
    for (int rep = 0; rep < 4; ++rep) {
        int task = t + 256 * rep;
        int c = task >> 3, s = task & 7;
        const float* Wsrc = (c < 64) ? (Wl + (size_t)c * 64)
                                     : (Wr + (size_t)(c - 64) * 64);
        float4 v0 = *(const float4*)(Wsrc + 8 * s);
        float4 v1 = *(const float4*)(Wsrc + 8 * s + 4);
        uint4 u;
        u.x = f2bf(v0.x) | (f2bf(v0.y) << 16);
        u.y = f2bf(v0.z) | (f2bf(v0.w) << 16);
        u.z = f2bf(v1.x) | (f2bf(v1.y) << 16);
        u.w = f2bf(v1.z) | (f2bf(v1.w) << 16);
        *(uint4*)(Bls + c * 72 + 8 * s) = u;
    }
    __syncthreads();

    const int r = lane & 15, g = lane >> 4;
    const int cw0 = 32 * w;

    bf16x8 bf[2][2];
    #pragma unroll
    for (int ct = 0; ct < 2; ++ct)
        #pragma unroll
        for (int ks = 0; ks < 2; ++ks) {
            int c = cw0 + 16 * ct + r;
            bf[ct][ks] = *(const bf16x8*)(Bls + c * 72 + (ks * 4 + g) * 8);
        }

    f32x4 acc[4][2];
    #pragma unroll
    for (int nt = 0; nt < 4; ++nt)
        #pragma unroll
        for (int ct = 0; ct < 2; ++ct)
            acc[nt][ct] = (f32x4){0.f, 0.f, 0.f, 0.f};

    #pragma unroll
    for (int nt = 0; nt < 4; ++nt) {
        bf16x8 af[2];
        #pragma unroll
        for (int ks = 0; ks < 2; ++ks)
            af[ks] = *(const bf16x8*)(Als + (nt * 16 + r) * 72 + (ks * 4 + g) * 8);
        #pragma unroll
        for (int ct = 0; ct < 2; ++ct)
            #pragma unroll
            for (int ks = 0; ks < 2; ++ks)
                acc[nt][ct] = __builtin_amdgcn_mfma_f32_16x16x32_bf16(
                    af[ks], bf[ct][ks], acc[nt][ct], 0, 0, 0);
    }

    unsigned short* Tb = (unsigned short*)outt;
    unsigned short* Rb = (unsigned short*)outr;
    #pragma unroll
    for (int ct = 0; ct < 2; ++ct) {
        int c = cw0 + 16 * ct + r;
        float badd = (c >= 64) ? bias[c - 64] : 0.f;
        unsigned short* dst = (c < 64) ? (Tb + c) : (Rb + (c - 64));
        #pragma unroll
        for (int nt = 0; nt < 4; ++nt)
            #pragma unroll
            for (int i = 0; i < 4; ++i) {
                int row = m0 + nt * 16 + g * 4 + i;
                if (row < NN)
                    dst[(size_t)row * 64] = (unsigned short)f2bf(acc[nt][ct][i] + badd);
            }
    }
}

// ---------------------------------------------------------------------------
// FUSED: blocks [0, B1_BLOCKS) bucket edges; blocks [B1_BLOCKS, ..) layer-1
// GEMM. B1 uses PER-WAVE histograms and offset counters (4 copies) to cut
// same-address LDS-atomic serialization 4x. Stage layout per bucket is
// [wave0|wave1|wave2|wave3]; flush math unchanged.
__global__ __launch_bounds__(256) void b1_gemm1_kernel(
    const void* ei, const int* flag,
    int* __restrict__ bcnt, int* __restrict__ bpk,
    const float* __restrict__ x,
    const float* __restrict__ W1l, const float* __restrict__ W1r,
    const float* __restrict__ b1,
    unsigned* __restrict__ T, unsigned* __restrict__ R)
{
    __shared__ __align__(16) char smem[30784];
    const int t = threadIdx.x;

    if (blockIdx.x >= B1_BLOCKS) {
        if (blockIdx.x == B1_BLOCKS && t < 32) T[(size_t)NN * 32 + t] = 0u; // zero row
        gemm_mfma_body<0>(smem, x, W1l, W1r, b1, T, R, blockIdx.x - B1_BLOCKS, t);
        return;
    }

    // ---------------- B1 part ----------------
    int* stage = (int*)smem;                                     // 16384
    unsigned char* sbuck = (unsigned char*)(smem + 16384);       // 4096
    int* hw    = (int*)(smem + 20480);                           // [4][256] 4096
    int* scanb = (int*)(smem + 24576);                           // 1024
    int* gbase = (int*)(smem + 25600);                           // 1024
    int* lofsw = (int*)(smem + 26624);                           // [4][256] 4096
    int* wsum  = (int*)(smem + 30720);                           // 64

    const int is64 = *flag;
    const int e0 = blockIdx.x * CHUNK;
    const int nE = min(CHUNK, NE - e0);
    const int lane = t & 63, wvi = t >> 6;

    for (int i = t; i < 1024; i += 256) { hw[i] = 0; lofsw[i] = 0; }
    __syncthreads();

    int sr[16], dr[16];
    #pragma unroll
    for (int rr = 0; rr < 16; ++rr) {
        int e = e0 + t + 256 * rr;
        if (e < NE) load_edge(ei, is64, e, sr[rr], dr[rr]);
        else dr[rr] = -1;
    }
    #pragma unroll
    for (int rr = 0; rr < 16; ++rr)
        if (dr[rr] >= 0) atomicAdd(&hw[wvi * 256 + (dr[rr] >> BSHIFT)], 1);
    __syncthreads();

    // per-bucket totals + per-wave bases; block-wide exclusive scan of totals
    int c0 = hw[0 * 256 + t], c1 = hw[1 * 256 + t],
        c2 = hw[2 * 256 + t], c3 = hw[3 * 256 + t];
    int tot = c0 + c1 + c2 + c3;
    hw[0 * 256 + t] = 0;
    hw[1 * 256 + t] = c0;
    hw[2 * 256 + t] = c0 + c1;
    hw[3 * 256 + t] = c0 + c1 + c2;
    int s = wave_incl_scan(tot, lane);
    if (lane == 63) wsum[wvi] = s;
    __syncthreads();     // protects wsum AND hw per-wave bases
    int add = 0;
    #pragma unroll
    for (int k = 0; k < 3; ++k) if (wvi > k) add += wsum[k];
    s += add;
    scanb[t] = s - tot;
    if (t < NBUCK) gbase[t] = atomicAdd(&bcnt[t], tot);
    __syncthreads();     // protects scanb/gbase

    #pragma unroll
    for (int rr = 0; rr < 16; ++rr) {
        if (dr[rr] >= 0) {
            int b = dr[rr] >> BSHIFT;
            int p = scanb[b] + hw[wvi * 256 + b]
                  + atomicAdd(&lofsw[wvi * 256 + b], 1);
            stage[p] = (sr[rr] << BSHIFT) | (dr[rr] & (BWIDTH - 1));
            sbuck[p] = (unsigned char)b;
        }
    }
    __syncthreads();

    for (int i = t; i < nE; i += 256) {
        int b = sbuck[i];
        int off = gbase[b] + (i - scanb[b]);
        if (off < SLOTS) bpk[(size_t)b * SLOTS + off] = stage[i];
    }
}

// ---------------------------------------------------------------------------
// B3 (512 threads): packed bucket -> rowptr + colb (byte offsets), with
// in-block bucket prefix; all scans via wave shfl.
__global__ __launch_bounds__(512) void bucket_to_csr_kernel(
    const int* __restrict__ bcnt, const int* __restrict__ bpk,
    int* __restrict__ rowptr, int* __restrict__ colb)
{
    __shared__ int ldeg[512], lptr[512], lcnt[512], sc[512], wsum[8];
    const int t = threadIdx.x, b = blockIdx.x;
    const int lane = t & 63, wvi = t >> 6;

    int v = (t < NBUCK) ? bcnt[t] : 0;
    int s = wave_incl_scan(v, lane);
    if (lane == 63) wsum[wvi] = s;
    __syncthreads();
    int add = 0;
    #pragma unroll
    for (int k = 0; k < 7; ++k) if (wvi > k) add += wsum[k];
    s += add;
    sc[t] = s;
    __syncthreads();
    const int base = (b == 0) ? 0 : sc[b - 1];
    if (b == 0 && t == 0) rowptr[NN] = NE;
    __syncthreads();

    ldeg[t] = 0; lcnt[t] = 0;
    __syncthreads();

    const int n0 = b << BSHIFT;
    const int cnt = min(bcnt[b], SLOTS);
    const int* src = bpk + (size_t)b * SLOTS;
    for (int i = t; i < cnt; i += 512)
        atomicAdd(&ldeg[src[i] & (BWIDTH - 1)], 1);
    __syncthreads();

    int a = ldeg[t];
    int s2 = wave_incl_scan(a, lane);
    if (lane == 63) wsum[wvi] = s2;
    __syncthreads();
    int add2 = 0;
    #pragma unroll
    for (int k = 0; k < 7; ++k) if (wvi > k) add2 += wsum[k];
    s2 += add2;
    lptr[t] = s2 - a;
    __syncthreads();

    int gn = n0 + t;
    if (gn < NN) rowptr[gn] = base + lptr[t];

    for (int i = t; i < cnt; i += 512) {
        int p = src[i];
        int li = p & (BWIDTH - 1);
        int pos = lptr[li] + atomicAdd(&lcnt[li], 1);
        colb[base + pos] = (p >> BSHIFT) << 7;   // src byte offset into table
    }
}

// ---------------------------------------------------------------------------
// Standalone layer-2 MFMA GEMM (bf16 input features; in-place safe per-tile).
__global__ __launch_bounds__(256) void gemm2_kernel(
    const unsigned* __restrict__ feat,
    const float* __restrict__ Wl, const float* __restrict__ Wr,
    const float* __restrict__ bias,
    unsigned* __restrict__ outt, unsigned* __restrict__ outr)
{
    __shared__ __align__(16) char smem[27648];
    gemm_mfma_body<1>(smem, feat, Wl, Wr, bias, outt, outr, blockIdx.x, threadIdx.x);
}

// ---------------------------------------------------------------------------
// Gather-mean (bf16 table) + epilogue. Block = 8 nodes; col range staged in
// LDS (contiguous). FINAL=0: rh <- relu(mean + rh) (bf16, global).
// FINAL=1: h2 kept in LDS only; fused head computes out = h2 @ Wlin.T + blin.
// wls stride 68: head reads are 2-way broadcast (free), round-17 fix.
#define AGG_STEP(O0, O1, O2, O3)                                              \
    {                                                                         \
        int o0 = O0, o1 = O1, o2 = O2, o3 = O3;                               \
        o0 = (jj      < end) ? o0 : zoff;                                     \
        o1 = (jj + 4  < end) ? o1 : zoff;                                     \
        o2 = (jj + 8  < end) ? o2 : zoff;                                     \
        o3 = (jj + 12 < end) ? o3 : zoff;                                     \
        uint4 u0 = *(const uint4*)(tb + (size_t)(unsigned)o0 + 16 * c8);      \
        uint4 u1 = *(const uint4*)(tb + (size_t)(unsigned)o1 + 16 * c8);      \
        uint4 u2 = *(const uint4*)(tb + (size_t)(unsigned)o2 + 16 * c8);      \
        uint4 u3 = *(const uint4*)(tb + (size_t)(unsigned)o3 + 16 * c8);      \
        a0 += unpk(u0.x); a1 += unpk(u0.y); a2 += unpk(u0.z); a3 += unpk(u0.w);\
        b0 += unpk(u1.x); b1 += unpk(u1.y); b2 += unpk(u1.z); b3 += unpk(u1.w);\
        a0 += unpk(u2.x); a1 += unpk(u2.y); a2 += unpk(u2.z); a3 += unpk(u2.w);\
        b0 += unpk(u3.x); b1 += unpk(u3.y); b2 += unpk(u3.z); b3 += unpk(u3.w);\
    }

template<int FINAL>
__global__ void aggregate_relu_kernel(const int* __restrict__ rowptr,
                                      const int* __restrict__ colb,
                                      const unsigned* __restrict__ tt,  // (NN+1) x 32
                                      unsigned* rh,                     // NN x 32
                                      const float* __restrict__ Wlin,
                                      const float* __restrict__ blin,
                                      float* __restrict__ out) {
    __shared__ int lcol[AGG_CAP];
    __shared__ float wls[16 * 68];                // Wlin, stride 68 (FINAL only)
    __shared__ unsigned short hbuf[8][72];        // h2 rows (FINAL only)
    const int t = threadIdx.x;
    const int n0 = blockIdx.x * 8;
    const int lane = t & 63;
    const int w = t >> 6;
    const int half = lane >> 5;
    const int slot = (lane >> 3) & 3;
    const int c8   = lane & 7;
    const int node = n0 + 2 * w + half;           // NN % 8 == 0 -> always < NN

    const int cbeg  = rowptr[n0];
    const int cendB = rowptr[min(n0 + 8, NN)];
    const int total = cendB - cbeg;
    const bool fast = (total <= AGG_CAP);
    if (fast) {
        for (int i = t; i < total; i += 256) lcol[i] = colb[cbeg + i];
    }
    if (FINAL) {
        for (int i = t; i < 1024; i += 256) {
            int cc = i >> 6, k = i & 63;
            wls[cc * 68 + k] = Wlin[i];
        }
    }
    __syncthreads();

    const int beg = rowptr[node], end = rowptr[node + 1];
    const int deg = end - beg;
    int niter = (deg + 3) >> 2;
    niter = max(niter, __shfl_xor(niter, 32));   // wave-uniform

    const char* tb = (const char*)tt;
    const int zoff = NN * 128;                   // zero row (byte offset)
    v2f a0 = {0.f, 0.f}, a1 = {0.f, 0.f}, a2 = {0.f, 0.f}, a3 = {0.f, 0.f};
    v2f b0 = {0.f, 0.f}, b1 = {0.f, 0.f}, b2 = {0.f, 0.f}, b3 = {0.f, 0.f};

    int jj = beg + slot;
    int it = 0;
    if (fast) {
        for (; it + 4 <= niter; it += 4, jj += 16) {
            int jc0 = min(jj,      end - 1) - cbeg;
            int jc1 = min(jj + 4,  end - 1) - cbeg;
            int jc2 = min(jj + 8,  end - 1) - cbeg;
            int jc3 = min(jj + 12, end - 1) - cbeg;
            AGG_STEP(lcol[jc0], lcol[jc1], lcol[jc2], lcol[jc3])
        }
        for (; it < niter; ++it, jj += 4) {
            int jc0 = min(jj, end - 1) - cbeg;
            int o0 = lcol[jc0];
            o0 = (jj < end) ? o0 : zoff;
            uint4 u0 = *(const uint4*)(tb + (size_t)(unsigned)o0 + 16 * c8);
            a0 += unpk(u0.x); a1 += unpk(u0.y); a2 += unpk(u0.z); a3 += unpk(u0.w);
        }
    } else {
        for (; it + 4 <= niter; it += 4, jj += 16) {
            int jc0 = min(jj,      end - 1);
            int jc1 = min(jj + 4,  end - 1);
            int jc2 = min(jj + 8,  end - 1);
            int jc3 = min(jj + 12, end - 1);
            AGG_STEP(colb[jc0], colb[jc1], colb[jc2], colb[jc3])
        }
        for (; it < niter; ++it, jj += 4) {
            int jc0 = min(jj, end - 1);
            int o0 = colb[jc0];
            o0 = (jj < end) ? o0 : zoff;
            uint4 u0 = *(const uint4*)(tb + (size_t)(unsigned)o0 + 16 * c8);
            a0 += unpk(u0.x); a1 += unpk(u0.y); a2 += unpk(u0.z); a3 += unpk(u0.w);
        }
    }
    a0 += b0; a1 += b1; a2 += b2; a3 += b3;

    a0[0] += __shfl_xor(a0[0], 8);  a0[1] += __shfl_xor(a0[1], 8);
    a1[0] += __shfl_xor(a1[0], 8);  a1[1] += __shfl_xor(a1[1], 8);
    a2[0] += __shfl_xor(a2[0], 8);  a2[1] += __shfl_xor(a2[1], 8);
    a3[0] += __shfl_xor(a3[0], 8);  a3[1] += __shfl_xor(a3[1], 8);
    a0[0] += __shfl_xor(a0[0], 16); a0[1] += __shfl_xor(a0[1], 16);
    a1[0] += __shfl_xor(a1[0], 16); a1[1] += __shfl_xor(a1[1], 16);
    a2[0] += __shfl_xor(a2[0], 16); a2[1] += __shfl_xor(a2[1], 16);
    a3[0] += __shfl_xor(a3[0], 16); a3[1] += __shfl_xor(a3[1], 16);

    if (slot == 0) {
        float inv = 1.0f / fmaxf((float)deg, 1.0f);
        unsigned* p = rh + (size_t)node * 32 + 4 * c8;
        uint4 rr = *(const uint4*)p;
        v2f q0 = unpk(rr.x), q1 = unpk(rr.y), q2 = unpk(rr.z), q3 = unpk(rr.w);
        float h0 = fmaxf(fmaf(a0[0], inv, q0[0]), 0.0f);
        float h1 = fmaxf(fmaf(a0[1], inv, q0[1]), 0.0f);
        float h2 = fmaxf(fmaf(a1[0], inv, q1[0]), 0.0f);
        float h3 = fmaxf(fmaf(a1[1], inv, q1[1]), 0.0f);
        float h4 = fmaxf(fmaf(a2[0], inv, q2[0]), 0.0f);
        float h5 = fmaxf(fmaf(a2[1], inv, q2[1]), 0.0f);
        float h6 = fmaxf(fmaf(a3[0], inv, q3[0]), 0.0f);
        float h7 = fmaxf(fmaf(a3[1], inv, q3[1]), 0.0f);
        uint4 wv4;
        wv4.x = f2bf(h0) | (f2bf(h1) << 16);
        wv4.y = f2bf(h2) | (f2bf(h3) << 16);
        wv4.z = f2bf(h4) | (f2bf(h5) << 16);
        wv4.w = f2bf(h6) | (f2bf(h7) << 16);
        if (FINAL) {
            *(uint4*)&hbuf[2 * w + half][8 * c8] = wv4;   // LDS only
        } else {
            *(uint4*)p = wv4;                              // h1 to global
        }
    }

    if (FINAL) {
        __syncthreads();
        // head: 128 threads, thread = (node i = t>>4, out ch cc = t&15)
        if (t < 128) {
            int i = t >> 4, cc = t & 15;
            int gnode = n0 + i;
            const unsigned* hrow = (const unsigned*)hbuf[i];
            float acc = blin[cc];
            #pragma unroll
            for (int k2 = 0; k2 < 32; ++k2) {
                v2f hv = unpk(hrow[k2]);
                acc = fmaf(hv[0], wls[cc * 68 + 2 * k2], acc);
                acc = fmaf(hv[1], wls[cc * 68 + 2 * k2 + 1], acc);
            }
            if (gnode < NN)
                out[(size_t)gnode * 16 + cc] = acc;
        }
    }
}

// ---------------------------------------------------------------------------
extern "C" void kernel_launch(void* const* d_in, const int* in_sizes, int n_in,
                              void* d_out, int out_size, void* d_ws, size_t ws_size,
                              hipStream_t stream) {
    const float* x    = (const float*)d_in[0];
    const void*  ei   = d_in[1];
    const float* W1l  = (const float*)d_in[2];
    const float* b1   = (const float*)d_in[3];
    const float* W1r  = (const float*)d_in[4];
    const float* W2l  = (const float*)d_in[5];
    const float* b2   = (const float*)d_in[6];
    const float* W2r  = (const float*)d_in[7];
    const float* Wlin = (const float*)d_in[8];
    const float* blin = (const float*)d_in[9];
    float* out = (float*)d_out;

    char* w = (char*)d_ws;
    int*      flag   = (int*)w;                                   // @ 0
    int*      bcnt   = (int*)(w + (size_t)4 * 1024);              // @ 4K
    int*      rowptr = (int*)(w + (size_t)1024 * 1024);           // @ 1M  (400 KB+4)
    int*      colb   = (int*)(w + (size_t)2 * 1024 * 1024);       // @ 2M  (6.4 MB)
    int*      bpk    = (int*)(w + (size_t)10 * 1024 * 1024);      // @ 10M (9.6 MB packed)
    unsigned* T      = (unsigned*)(w + (size_t)30 * 1024 * 1024); // @ 30M (12.8 MB + zero row)
    unsigned* R      = (unsigned*)(w + (size_t)43 * 1024 * 1024); // @ 43M (12.8 MB bf16 r/h)

    detect_mode_kernel<<<1, 256, 0, stream>>>((const int*)ei, flag, bcnt);

    // ---- fused: B1 (blocks 0..390) + layer-1 MFMA GEMM (blocks 391..) ----
    b1_gemm1_kernel<<<B1_BLOCKS + GEMM_BLOCKS, 256, 0, stream>>>(
        ei, flag, bcnt, bpk, x, W1l, W1r, b1, T, R);

    bucket_to_csr_kernel<<<NBUCK, 512, 0, stream>>>(bcnt, bpk, rowptr, colb);

    const int aggBlocks = (NN + 7) / 8;        // 12500 (8 nodes per block)

    aggregate_relu_kernel<0><<<aggBlocks, 256, 0, stream>>>(
        rowptr, colb, T, R, nullptr, nullptr, nullptr);           // h1 in R

    gemm2_kernel<<<GEMM_BLOCKS, 256, 0, stream>>>(R, W2l, W2r, b2, T, R);

    // final aggregate + fused head (h2 never hits global)
    aggregate_relu_kernel<1><<<aggBlocks, 256, 0, stream>>>(
        rowptr, colb, T, R, Wlin, blin, out);
}

// Round 20
// 140.816 us; speedup vs baseline: 1.0414x; 1.0300x over previous
//
#include <hip/hip_runtime.h>

#define NN 100000
#define NE 1600000
// IN_CH = HID = 64, OUT_CH = 16

// ---- bucketed CSR build geometry ----
#define BSHIFT 9
#define BWIDTH 512
#define NBUCK 196
#define SLOTS 12288
#define CHUNK 4096                               // edges per B1 block
#define B1_BLOCKS ((NE + CHUNK - 1) / CHUNK)     // 391
#define GEMM_BLOCKS ((NN + 63) / 64)             // 1563
#define AGG_CAP 1024

typedef float    v2f __attribute__((ext_vector_type(2)));
typedef unsigned v2u __attribute__((ext_vector_type(2)));
typedef short    bf16x8 __attribute__((ext_vector_type(8)));
typedef float    f32x4  __attribute__((ext_vector_type(4)));

// ---- bf16 helpers ----
__device__ __forceinline__ float u2f(unsigned u) {
    union { unsigned u; float f; } v; v.u = u; return v.f;
}
__device__ __forceinline__ unsigned f2u(float f) {
    union { float f; unsigned u; } v; v.f = f; return v.u;
}
__device__ __forceinline__ unsigned f2bf(float f) {   // bf16 in low 16, RNE
    unsigned u = f2u(f);
    return (u + 0x7FFFu + ((u >> 16) & 1u)) >> 16;
}
// FAST unpack bf16x2 -> float2: hi half keeps the lo-channel's 16 bits as
// mantissa-extension garbage (rel. err <= 2^-17, four orders below bf16's
// own 2^-8 quantization). Saves the AND: 2 VALU/uint instead of 3.
__device__ __forceinline__ v2f unpk(unsigned x) {
    v2u w; w[0] = x << 16; w[1] = x;
    union { v2u u; v2f f; } c; c.u = w; return c.f;
}
// wave-level inclusive scan (64 lanes)
__device__ __forceinline__ int wave_incl_scan(int v, int lane) {
    #pragma unroll
    for (int off = 1; off < 64; off <<= 1) {
        int u = __shfl_up(v, off);
        if (lane >= off) v += u;
    }
    return v;
}

// ---------------------------------------------------------------------------
// Detect int64 vs int32 edge_index; also zeroes bcnt.
__global__ void detect_mode_kernel(const int* ei32, int* flag, int* bcnt) {
    __shared__ int any_nonzero;
    if (threadIdx.x == 0) any_nonzero = 0;
    if (threadIdx.x < NBUCK) bcnt[threadIdx.x] = 0;
    __syncthreads();
    int idx = 1 + 2 * threadIdx.x;
    if (ei32[idx] != 0) atomicOr(&any_nonzero, 1);
    __syncthreads();
    if (threadIdx.x == 0) flag[0] = (any_nonzero == 0) ? 1 : 0;  // 1 => int64
}

__device__ __forceinline__ void load_edge(const void* ei, int is64, int e,
                                          int& s, int& d) {
    if (is64) {
        const long long* p = (const long long*)ei;
        s = (int)p[e];
        d = (int)p[NE + e];
    } else {
        const int* p = (const int*)ei;
        s = p[e];
        d = p[NE + e];
    }
}

// ---------------------------------------------------------------------------
// MFMA GEMM body: t(bf16) = feat @ Wl.T ; r(bf16, +bias) = feat @ Wr.T.
// Block = 256 thr = 4 waves; tile 64 nodes x 128 ch; wave w owns 32 channels.
template<int BF16IN>
__device__ __forceinline__ void gemm_mfma_body(
    char* smem, const void* __restrict__ featv,
    const float* __restrict__ Wl, const float* __restrict__ Wr,
    const float* __restrict__ bias,
    unsigned* __restrict__ outt, unsigned* __restrict__ outr,
    int tile, int t)
{
    unsigned short* Als = (unsigned short*)smem;            // [64][72] bf16
    unsigned short* Bls = (unsigned short*)(smem + 9216);   // [128][72] bf16
    const int lane = t & 63, w = t >> 6;
    const int m0 = tile * 64;
    const float*    featf = (const float*)featv;
    const unsigned* featu = (const unsigned*)featv;

    #pragma unroll
    for (int rep = 0; rep < 2; ++rep) {
        int task = t + 256 * rep;
        int row = task >> 3, s = task & 7;
        int gn = m0 + row;
        uint4 u;
        if (BF16IN) {
            u = (gn < NN) ? *(const uint4*)(featu + (size_t)gn * 32 + 4 * s)
                          : make_uint4(0u, 0u, 0u, 0u);
        } else {
            if (gn < NN) {
                float4 v0 = *(const float4*)(featf + (size_t)gn * 64 + 8 * s);
                float4 v1 = *(const float4*)(featf + (size_t)gn * 64 + 8 * s + 4);
                u.x = f2bf(v0.x) | (f2bf(v0.y) << 16);
                u.y = f2bf(v0.z) | (f2bf(v0.w) << 16);
                u.z = f2bf(v1.x) | (f2bf(v1.y) << 16);
                u.w = f2bf(v1.z) | (f2bf(v1.w) << 16);
            } else u = make_uint4(0u, 0u, 0u, 0u);
        }
        *(uint4*)(Als + row * 72 + 8 * s) = u;
    }
    #pragma unroll
    for (int rep = 0; rep < 4; ++rep) {
        int task = t + 256 * rep;
        int c = task >> 3, s = task & 7;
        const float* Wsrc = (c < 64) ? (Wl + (size_t)c * 64)
                                     : (Wr + (size_t)(c - 64) * 64);
        float4 v0 = *(const float4*)(Wsrc + 8 * s);
        float4 v1 = *(const float4*)(Wsrc + 8 * s + 4);
        uint4 u;
        u.x = f2bf(v0.x) | (f2bf(v0.y) << 16);
        u.y = f2bf(v0.z) | (f2bf(v0.w) << 16);
        u.z = f2bf(v1.x) | (f2bf(v1.y) << 16);
        u.w = f2bf(v1.z) | (f2bf(v1.w) << 16);
        *(uint4*)(Bls + c * 72 + 8 * s) = u;
    }
    __syncthreads();

    const int r = lane & 15, g = lane >> 4;
    const int cw0 = 32 * w;

    bf16x8 bf[2][2];
    #pragma unroll
    for (int ct = 0; ct < 2; ++ct)
        #pragma unroll
        for (int ks = 0; ks < 2; ++ks) {
            int c = cw0 + 16 * ct + r;
            bf[ct][ks] = *(const bf16x8*)(Bls + c * 72 + (ks * 4 + g) * 8);
        }

    f32x4 acc[4][2];
    #pragma unroll
    for (int nt = 0; nt < 4; ++nt)
        #pragma unroll
        for (int ct = 0; ct < 2; ++ct)
            acc[nt][ct] = (f32x4){0.f, 0.f, 0.f, 0.f};

    #pragma unroll
    for (int nt = 0; nt < 4; ++nt) {
        bf16x8 af[2];
        #pragma unroll
        for (int ks = 0; ks < 2; ++ks)
            af[ks] = *(const bf16x8*)(Als + (nt * 16 + r) * 72 + (ks * 4 + g) * 8);
        #pragma unroll
        for (int ct = 0; ct < 2; ++ct)
            #pragma unroll
            for (int ks = 0; ks < 2; ++ks)
                acc[nt][ct] = __builtin_amdgcn_mfma_f32_16x16x32_bf16(
                    af[ks], bf[ct][ks], acc[nt][ct], 0, 0, 0);
    }

    unsigned short* Tb = (unsigned short*)outt;
    unsigned short* Rb = (unsigned short*)outr;
    #pragma unroll
    for (int ct = 0; ct < 2; ++ct) {
        int c = cw0 + 16 * ct + r;
        float badd = (c >= 64) ? bias[c - 64] : 0.f;
        unsigned short* dst = (c < 64) ? (Tb + c) : (Rb + (c - 64));
        #pragma unroll
        for (int nt = 0; nt < 4; ++nt)
            #pragma unroll
            for (int i = 0; i < 4; ++i) {
                int row = m0 + nt * 16 + g * 4 + i;
                if (row < NN)
                    dst[(size_t)row * 64] = (unsigned short)f2bf(acc[nt][ct][i] + badd);
            }
    }
}

// ---------------------------------------------------------------------------
// FUSED: blocks [0, B1_BLOCKS) bucket edges; blocks [B1_BLOCKS, ..) layer-1
// GEMM. B1 uses per-wave histograms/offset counters (4x less LDS-atomic
// contention).
__global__ __launch_bounds__(256) void b1_gemm1_kernel(
    const void* ei, const int* flag,
    int* __restrict__ bcnt, int* __restrict__ bpk,
    const float* __restrict__ x,
    const float* __restrict__ W1l, const float* __restrict__ W1r,
    const float* __restrict__ b1,
    unsigned* __restrict__ T, unsigned* __restrict__ R)
{
    __shared__ __align__(16) char smem[30784];
    const int t = threadIdx.x;

    if (blockIdx.x >= B1_BLOCKS) {
        if (blockIdx.x == B1_BLOCKS && t < 32) T[(size_t)NN * 32 + t] = 0u; // zero row
        gemm_mfma_body<0>(smem, x, W1l, W1r, b1, T, R, blockIdx.x - B1_BLOCKS, t);
        return;
    }

    // ---------------- B1 part ----------------
    int* stage = (int*)smem;                                     // 16384
    unsigned char* sbuck = (unsigned char*)(smem + 16384);       // 4096
    int* hw    = (int*)(smem + 20480);                           // [4][256] 4096
    int* scanb = (int*)(smem + 24576);                           // 1024
    int* gbase = (int*)(smem + 25600);                           // 1024
    int* lofsw = (int*)(smem + 26624);                           // [4][256] 4096
    int* wsum  = (int*)(smem + 30720);                           // 64

    const int is64 = *flag;
    const int e0 = blockIdx.x * CHUNK;
    const int nE = min(CHUNK, NE - e0);
    const int lane = t & 63, wvi = t >> 6;

    for (int i = t; i < 1024; i += 256) { hw[i] = 0; lofsw[i] = 0; }
    __syncthreads();

    int sr[16], dr[16];
    #pragma unroll
    for (int rr = 0; rr < 16; ++rr) {
        int e = e0 + t + 256 * rr;
        if (e < NE) load_edge(ei, is64, e, sr[rr], dr[rr]);
        else dr[rr] = -1;
    }
    #pragma unroll
    for (int rr = 0; rr < 16; ++rr)
        if (dr[rr] >= 0) atomicAdd(&hw[wvi * 256 + (dr[rr] >> BSHIFT)], 1);
    __syncthreads();

    int c0 = hw[0 * 256 + t], c1 = hw[1 * 256 + t],
        c2 = hw[2 * 256 + t], c3 = hw[3 * 256 + t];
    int tot = c0 + c1 + c2 + c3;
    hw[0 * 256 + t] = 0;
    hw[1 * 256 + t] = c0;
    hw[2 * 256 + t] = c0 + c1;
    hw[3 * 256 + t] = c0 + c1 + c2;
    int s = wave_incl_scan(tot, lane);
    if (lane == 63) wsum[wvi] = s;
    __syncthreads();
    int add = 0;
    #pragma unroll
    for (int k = 0; k < 3; ++k) if (wvi > k) add += wsum[k];
    s += add;
    scanb[t] = s - tot;
    if (t < NBUCK) gbase[t] = atomicAdd(&bcnt[t], tot);
    __syncthreads();

    #pragma unroll
    for (int rr = 0; rr < 16; ++rr) {
        if (dr[rr] >= 0) {
            int b = dr[rr] >> BSHIFT;
            int p = scanb[b] + hw[wvi * 256 + b]
                  + atomicAdd(&lofsw[wvi * 256 + b], 1);
            stage[p] = (sr[rr] << BSHIFT) | (dr[rr] & (BWIDTH - 1));
            sbuck[p] = (unsigned char)b;
        }
    }
    __syncthreads();

    for (int i = t; i < nE; i += 256) {
        int b = sbuck[i];
        int off = gbase[b] + (i - scanb[b]);
        if (off < SLOTS) bpk[(size_t)b * SLOTS + off] = stage[i];
    }
}

// ---------------------------------------------------------------------------
// B3 (512 threads): packed bucket -> rowptr + colb (byte offsets), with
// in-block bucket prefix; all scans via wave shfl.
__global__ __launch_bounds__(512) void bucket_to_csr_kernel(
    const int* __restrict__ bcnt, const int* __restrict__ bpk,
    int* __restrict__ rowptr, int* __restrict__ colb)
{
    __shared__ int ldeg[512], lptr[512], lcnt[512], sc[512], wsum[8];
    const int t = threadIdx.x, b = blockIdx.x;
    const int lane = t & 63, wvi = t >> 6;

    int v = (t < NBUCK) ? bcnt[t] : 0;
    int s = wave_incl_scan(v, lane);
    if (lane == 63) wsum[wvi] = s;
    __syncthreads();
    int add = 0;
    #pragma unroll
    for (int k = 0; k < 7; ++k) if (wvi > k) add += wsum[k];
    s += add;
    sc[t] = s;
    __syncthreads();
    const int base = (b == 0) ? 0 : sc[b - 1];
    if (b == 0 && t == 0) rowptr[NN] = NE;
    __syncthreads();

    ldeg[t] = 0; lcnt[t] = 0;
    __syncthreads();

    const int n0 = b << BSHIFT;
    const int cnt = min(bcnt[b], SLOTS);
    const int* src = bpk + (size_t)b * SLOTS;
    for (int i = t; i < cnt; i += 512)
        atomicAdd(&ldeg[src[i] & (BWIDTH - 1)], 1);
    __syncthreads();

    int a = ldeg[t];
    int s2 = wave_incl_scan(a, lane);
    if (lane == 63) wsum[wvi] = s2;
    __syncthreads();
    int add2 = 0;
    #pragma unroll
    for (int k = 0; k < 7; ++k) if (wvi > k) add2 += wsum[k];
    s2 += add2;
    lptr[t] = s2 - a;
    __syncthreads();

    int gn = n0 + t;
    if (gn < NN) rowptr[gn] = base + lptr[t];

    for (int i = t; i < cnt; i += 512) {
        int p = src[i];
        int li = p & (BWIDTH - 1);
        int pos = lptr[li] + atomicAdd(&lcnt[li], 1);
        colb[base + pos] = (p >> BSHIFT) << 7;   // src byte offset into table
    }
}

// ---------------------------------------------------------------------------
// Standalone layer-2 MFMA GEMM (bf16 input features; in-place safe per-tile).
__global__ __launch_bounds__(256) void gemm2_kernel(
    const unsigned* __restrict__ feat,
    const float* __restrict__ Wl, const float* __restrict__ Wr,
    const float* __restrict__ bias,
    unsigned* __restrict__ outt, unsigned* __restrict__ outr)
{
    __shared__ __align__(16) char smem[27648];
    gemm_mfma_body<1>(smem, feat, Wl, Wr, bias, outt, outr, blockIdx.x, threadIdx.x);
}

// ---------------------------------------------------------------------------
// Gather-mean (bf16 table) + epilogue. Block = 8 nodes; col range staged in
// LDS (contiguous). FINAL=0: rh <- relu(mean + rh) (bf16, global).
// FINAL=1: h2 kept in LDS only; fused head computes out = h2 @ Wlin.T + blin.
#define AGG_STEP(O0, O1, O2, O3)                                              \
    {                                                                         \
        int o0 = O0, o1 = O1, o2 = O2, o3 = O3;                               \
        o0 = (jj      < end) ? o0 : zoff;                                     \
        o1 = (jj + 4  < end) ? o1 : zoff;                                     \
        o2 = (jj + 8  < end) ? o2 : zoff;                                     \
        o3 = (jj + 12 < end) ? o3 : zoff;                                     \
        uint4 u0 = *(const uint4*)(tb + (size_t)(unsigned)o0 + 16 * c8);      \
        uint4 u1 = *(const uint4*)(tb + (size_t)(unsigned)o1 + 16 * c8);      \
        uint4 u2 = *(const uint4*)(tb + (size_t)(unsigned)o2 + 16 * c8);      \
        uint4 u3 = *(const uint4*)(tb + (size_t)(unsigned)o3 + 16 * c8);      \
        a0 += unpk(u0.x); a1 += unpk(u0.y); a2 += unpk(u0.z); a3 += unpk(u0.w);\
        b0 += unpk(u1.x); b1 += unpk(u1.y); b2 += unpk(u1.z); b3 += unpk(u1.w);\
        a0 += unpk(u2.x); a1 += unpk(u2.y); a2 += unpk(u2.z); a3 += unpk(u2.w);\
        b0 += unpk(u3.x); b1 += unpk(u3.y); b2 += unpk(u3.z); b3 += unpk(u3.w);\
    }

template<int FINAL>
__global__ void aggregate_relu_kernel(const int* __restrict__ rowptr,
                                      const int* __restrict__ colb,
                                      const unsigned* __restrict__ tt,  // (NN+1) x 32
                                      unsigned* rh,                     // NN x 32
                                      const float* __restrict__ Wlin,
                                      const float* __restrict__ blin,
                                      float* __restrict__ out) {
    __shared__ int lcol[AGG_CAP];
    __shared__ float wls[16 * 68];                // Wlin, stride 68 (FINAL only)
    __shared__ unsigned short hbuf[8][72];        // h2 rows (FINAL only)
    const int t = threadIdx.x;
    const int n0 = blockIdx.x * 8;
    const int lane = t & 63;
    const int w = t >> 6;
    const int half = lane >> 5;
    const int slot = (lane >> 3) & 3;
    const int c8   = lane & 7;
    const int node = n0 + 2 * w + half;           // NN % 8 == 0 -> always < NN

    const int cbeg  = rowptr[n0];
    const int cendB = rowptr[min(n0 + 8, NN)];
    const int total = cendB - cbeg;
    const bool fast = (total <= AGG_CAP);
    if (fast) {
        for (int i = t; i < total; i += 256) lcol[i] = colb[cbeg + i];
    }
    if (FINAL) {
        for (int i = t; i < 1024; i += 256) {
            int cc = i >> 6, k = i & 63;
            wls[cc * 68 + k] = Wlin[i];
        }
    }
    __syncthreads();

    const int beg = rowptr[node], end = rowptr[node + 1];
    const int deg = end - beg;
    int niter = (deg + 3) >> 2;
    niter = max(niter, __shfl_xor(niter, 32));   // wave-uniform

    const char* tb = (const char*)tt;
    const int zoff = NN * 128;                   // zero row (byte offset)
    v2f a0 = {0.f, 0.f}, a1 = {0.f, 0.f}, a2 = {0.f, 0.f}, a3 = {0.f, 0.f};
    v2f b0 = {0.f, 0.f}, b1 = {0.f, 0.f}, b2 = {0.f, 0.f}, b3 = {0.f, 0.f};

    int jj = beg + slot;
    int it = 0;
    if (fast) {
        for (; it + 4 <= niter; it += 4, jj += 16) {
            int jc0 = min(jj,      end - 1) - cbeg;
            int jc1 = min(jj + 4,  end - 1) - cbeg;
            int jc2 = min(jj + 8,  end - 1) - cbeg;
            int jc3 = min(jj + 12, end - 1) - cbeg;
            AGG_STEP(lcol[jc0], lcol[jc1], lcol[jc2], lcol[jc3])
        }
        for (; it < niter; ++it, jj += 4) {
            int jc0 = min(jj, end - 1) - cbeg;
            int o0 = lcol[jc0];
            o0 = (jj < end) ? o0 : zoff;
            uint4 u0 = *(const uint4*)(tb + (size_t)(unsigned)o0 + 16 * c8);
            a0 += unpk(u0.x); a1 += unpk(u0.y); a2 += unpk(u0.z); a3 += unpk(u0.w);
        }
    } else {
        for (; it + 4 <= niter; it += 4, jj += 16) {
            int jc0 = min(jj,      end - 1);
            int jc1 = min(jj + 4,  end - 1);
            int jc2 = min(jj + 8,  end - 1);
            int jc3 = min(jj + 12, end - 1);
            AGG_STEP(colb[jc0], colb[jc1], colb[jc2], colb[jc3])
        }
        for (; it < niter; ++it, jj += 4) {
            int jc0 = min(jj, end - 1);
            int o0 = colb[jc0];
            o0 = (jj < end) ? o0 : zoff;
            uint4 u0 = *(const uint4*)(tb + (size_t)(unsigned)o0 + 16 * c8);
            a0 += unpk(u0.x); a1 += unpk(u0.y); a2 += unpk(u0.z); a3 += unpk(u0.w);
        }
    }
    a0 += b0; a1 += b1; a2 += b2; a3 += b3;

    a0[0] += __shfl_xor(a0[0], 8);  a0[1] += __shfl_xor(a0[1], 8);
    a1[0] += __shfl_xor(a1[0], 8);  a1[1] += __shfl_xor(a1[1], 8);
    a2[0] += __shfl_xor(a2[0], 8);  a2[1] += __shfl_xor(a2[1], 8);
    a3[0] += __shfl_xor(a3[0], 8);  a3[1] += __shfl_xor(a3[1], 8);
    a0[0] += __shfl_xor(a0[0], 16); a0[1] += __shfl_xor(a0[1], 16);
    a1[0] += __shfl_xor(a1[0], 16); a1[1] += __shfl_xor(a1[1], 16);
    a2[0] += __shfl_xor(a2[0], 16); a2[1] += __shfl_xor(a2[1], 16);
    a3[0] += __shfl_xor(a3[0], 16); a3[1] += __shfl_xor(a3[1], 16);

    if (slot == 0) {
        float inv = 1.0f / fmaxf((float)deg, 1.0f);
        unsigned* p = rh + (size_t)node * 32 + 4 * c8;
        uint4 rr = *(const uint4*)p;
        v2f q0 = unpk(rr.x), q1 = unpk(rr.y), q2 = unpk(rr.z), q3 = unpk(rr.w);
        float h0 = fmaxf(fmaf(a0[0], inv, q0[0]), 0.0f);
        float h1 = fmaxf(fmaf(a0[1], inv, q0[1]), 0.0f);
        float h2 = fmaxf(fmaf(a1[0], inv, q1[0]), 0.0f);
        float h3 = fmaxf(fmaf(a1[1], inv, q1[1]), 0.0f);
        float h4 = fmaxf(fmaf(a2[0], inv, q2[0]), 0.0f);
        float h5 = fmaxf(fmaf(a2[1], inv, q2[1]), 0.0f);
        float h6 = fmaxf(fmaf(a3[0], inv, q3[0]), 0.0f);
        float h7 = fmaxf(fmaf(a3[1], inv, q3[1]), 0.0f);
        uint4 wv4;
        wv4.x = f2bf(h0) | (f2bf(h1) << 16);
        wv4.y = f2bf(h2) | (f2bf(h3) << 16);
        wv4.z = f2bf(h4) | (f2bf(h5) << 16);
        wv4.w = f2bf(h6) | (f2bf(h7) << 16);
        if (FINAL) {
            *(uint4*)&hbuf[2 * w + half][8 * c8] = wv4;   // LDS only
        } else {
            *(uint4*)p = wv4;                              // h1 to global
        }
    }

    if (FINAL) {
        __syncthreads();
        if (t < 128) {
            int i = t >> 4, cc = t & 15;
            int gnode = n0 + i;
            const unsigned* hrow = (const unsigned*)hbuf[i];
            float acc = blin[cc];
            #pragma unroll
            for (int k2 = 0; k2 < 32; ++k2) {
                v2f hv = unpk(hrow[k2]);
                acc = fmaf(hv[0], wls[cc * 68 + 2 * k2], acc);
                acc = fmaf(hv[1], wls[cc * 68 + 2 * k2 + 1], acc);
            }
            if (gnode < NN)
                out[(size_t)gnode * 16 + cc] = acc;
        }
    }
}

// ---------------------------------------------------------------------------
extern "C" void kernel_launch(void* const* d_in, const int* in_sizes, int n_in,
                              void* d_out, int out_size, void* d_ws, size_t ws_size,
                              hipStream_t stream) {
    const float* x    = (const float*)d_in[0];
    const void*  ei   = d_in[1];
    const float* W1l  = (const float*)d_in[2];
    const float* b1   = (const float*)d_in[3];
    const float* W1r  = (const float*)d_in[4];
    const float* W2l  = (const float*)d_in[5];
    const float* b2   = (const float*)d_in[6];
    const float* W2r  = (const float*)d_in[7];
    const float* Wlin = (const float*)d_in[8];
    const float* blin = (const float*)d_in[9];
    float* out = (float*)d_out;

    char* w = (char*)d_ws;
    int*      flag   = (int*)w;                                   // @ 0
    int*      bcnt   = (int*)(w + (size_t)4 * 1024);              // @ 4K
    int*      rowptr = (int*)(w + (size_t)1024 * 1024);           // @ 1M  (400 KB+4)
    int*      colb   = (int*)(w + (size_t)2 * 1024 * 1024);       // @ 2M  (6.4 MB)
    int*      bpk    = (int*)(w + (size_t)10 * 1024 * 1024);      // @ 10M (9.6 MB packed)
    unsigned* T      = (unsigned*)(w + (size_t)30 * 1024 * 1024); // @ 30M (12.8 MB + zero row)
    unsigned* R      = (unsigned*)(w + (size_t)43 * 1024 * 1024); // @ 43M (12.8 MB bf16 r/h)

    detect_mode_kernel<<<1, 256, 0, stream>>>((const int*)ei, flag, bcnt);

    // ---- fused: B1 (blocks 0..390) + layer-1 MFMA GEMM (blocks 391..) ----
    b1_gemm1_kernel<<<B1_BLOCKS + GEMM_BLOCKS, 256, 0, stream>>>(
        ei, flag, bcnt, bpk, x, W1l, W1r, b1, T, R);

    bucket_to_csr_kernel<<<NBUCK, 512, 0, stream>>>(bcnt, bpk, rowptr, colb);

    const int aggBlocks = (NN + 7) / 8;        // 12500 (8 nodes per block)

    aggregate_relu_kernel<0><<<aggBlocks, 256, 0, stream>>>(
        rowptr, colb, T, R, nullptr, nullptr, nullptr);           // h1 in R

    gemm2_kernel<<<GEMM_BLOCKS, 256, 0, stream>>>(R, W2l, W2r, b2, T, R);

    // final aggregate + fused head (h2 never hits global)
    aggregate_relu_kernel<1><<<aggBlocks, 256, 0, stream>>>(
        rowptr, colb, T, R, Wlin, blin, out);
}